// Round 14
// baseline (925.247 us; speedup 1.0000x reference)
//
#include <hip/hip_runtime.h>

#define NN   500000
#define NE   16000000
#define NBIN 1954        // ceil(NN/256); node bin = node >> 8 (path B)

// ---- path A: two-level partition (needs ~141 MB ws, proven present in R11/R12) ----
#define NBUCK   245      // ceil(NN/2048); bucket = dst >> 11
#define NWGA    1000
#define CHUNKA4 4000     // (NE/NWGA)/4
// ---- path B: fallback = R9 single-level (91.6 MB ws) ----
#define NWGB    2000
#define CHUNKB4 2000
#define CAP     14336

typedef int      vint4   __attribute__((ext_vector_type(4)));
typedef float    vfloat4 __attribute__((ext_vector_type(4)));
typedef float    vfloat2 __attribute__((ext_vector_type(2)));
typedef _Float16 vhalf4  __attribute__((ext_vector_type(4)));
typedef _Float16 vhalf2  __attribute__((ext_vector_type(2)));

// ---- generic per-WG histogram over dst>>shift (LDS atomics only) ----
__global__ __launch_bounds__(256) void hist_kernel(const int* __restrict__ dst,
                                                   int* __restrict__ wgHist,
                                                   int shift, int nbin, int chunk4) {
    __shared__ int hist[NBIN];
    for (int i = threadIdx.x; i < nbin; i += 256) hist[i] = 0;
    __syncthreads();
    const vint4* d4 = (const vint4*)(dst + (size_t)blockIdx.x * chunk4 * 4);
    for (int i = threadIdx.x; i < chunk4; i += 256) {
        vint4 d = __builtin_nontemporal_load(d4 + i);
        atomicAdd(&hist[d.x >> shift], 1);
        atomicAdd(&hist[d.y >> shift], 1);
        atomicAdd(&hist[d.z >> shift], 1);
        atomicAdd(&hist[d.w >> shift], 1);
    }
    __syncthreads();
    int* row = wgHist + (size_t)blockIdx.x * nbin;
    for (int i = threadIdx.x; i < nbin; i += 256) row[i] = hist[i];
}

// ---- per-bin exclusive scan across WGs: one block per bin ----
__global__ __launch_bounds__(256) void scanbins_kernel(int* __restrict__ wgHist,
                                                       int* __restrict__ binTotal,
                                                       int nwg, int nbin) {
    __shared__ int partials[256];
    int bin = blockIdx.x;
    int t = threadIdx.x;
    int per = (nwg + 255) / 256;
    int w0 = t * per;
    int w1 = w0 + per; if (w1 > nwg) w1 = nwg;
    int s = 0;
    for (int w = w0; w < w1; ++w) s += wgHist[(size_t)w * nbin + bin];
    partials[t] = s;
    __syncthreads();
    if (t == 0) {
        int run = 0;
        for (int i = 0; i < 256; ++i) { int tmp = partials[i]; partials[i] = run; run += tmp; }
        binTotal[bin] = run;
    }
    __syncthreads();
    int off = partials[t];
    for (int w = w0; w < w1; ++w) {
        size_t idx = (size_t)w * nbin + bin;
        int v = wgHist[idx];
        wgHist[idx] = off;
        off += v;
    }
}

// ---- exclusive scan over bins (nbin <= 2048) ----
__global__ void scantotal_kernel(const int* __restrict__ binTotal, int* __restrict__ binStart,
                                 int nbin) {
    __shared__ int partials[512];
    int t = threadIdx.x;
    int base = t * 4;
    int v[4]; int s = 0;
#pragma unroll
    for (int j = 0; j < 4; ++j) {
        int b = base + j;
        v[j] = (b < nbin) ? binTotal[b] : 0;
        s += v[j];
    }
    partials[t] = s;
    __syncthreads();
    if (t == 0) {
        int run = 0;
        for (int i = 0; i < 512; ++i) { int tmp = partials[i]; partials[i] = run; run += tmp; }
        binStart[nbin] = run;  // == NE
    }
    __syncthreads();
    int off = partials[t];
#pragma unroll
    for (int j = 0; j < 4; ++j) {
        int b = base + j;
        if (b < nbin) binStart[b] = off;
        off += v[j];
    }
}

// ---- generic scatter into bins; pack (src<<shift)|(dst&mask); normal stores ----
__global__ __launch_bounds__(256) void reorder_kernel(const int* __restrict__ src,
                                                      const int* __restrict__ dst,
                                                      const int* __restrict__ wgHist,
                                                      const int* __restrict__ binStart,
                                                      int* __restrict__ outbuf,
                                                      int shift, int nbin, int chunk4) {
    __shared__ int cur[NBIN];
    const int* row = wgHist + (size_t)blockIdx.x * nbin;
    for (int i = threadIdx.x; i < nbin; i += 256) cur[i] = binStart[i] + row[i];
    __syncthreads();
    const int mask = (1 << shift) - 1;
    const vint4* s4 = (const vint4*)(src + (size_t)blockIdx.x * chunk4 * 4);
    const vint4* d4 = (const vint4*)(dst + (size_t)blockIdx.x * chunk4 * 4);
    for (int i = threadIdx.x; i < chunk4; i += 256) {
        vint4 s = __builtin_nontemporal_load(s4 + i);
        vint4 d = __builtin_nontemporal_load(d4 + i);
        int ss[4] = {s.x, s.y, s.z, s.w};
        int dd[4] = {d.x, d.y, d.z, d.w};
#pragma unroll
        for (int k = 0; k < 4; ++k) {
            int pos = atomicAdd(&cur[dd[k] >> shift], 1);
            outbuf[pos] = (ss[k] << shift) | (dd[k] & mask);
        }
    }
}

// ---- path A pass 2a: per-bucket counts -> rowStart/dinv/p1 (no scatter) ----
__global__ __launch_bounds__(512) void count_kernel(const int* __restrict__ bktStart,
                                                    const int* __restrict__ bucketbuf,
                                                    const float* __restrict__ x,
                                                    float* __restrict__ dinv,
                                                    float* __restrict__ p1,
                                                    int* __restrict__ rowStart) {
    __shared__ int cnt[2048];
    __shared__ int partials[512];
    int b = blockIdx.x, t = threadIdx.x;
    for (int k = t; k < 2048; k += 512) cnt[k] = 0;
    __syncthreads();
    int e0 = bktStart[b], e1 = bktStart[b + 1];
    int i = e0 + t;
    for (; i + 3 * 512 < e1; i += 4 * 512) {
        int a = __builtin_nontemporal_load(bucketbuf + i);
        int c = __builtin_nontemporal_load(bucketbuf + i + 512);
        int d = __builtin_nontemporal_load(bucketbuf + i + 1024);
        int e = __builtin_nontemporal_load(bucketbuf + i + 1536);
        atomicAdd(&cnt[a & 2047], 1);
        atomicAdd(&cnt[c & 2047], 1);
        atomicAdd(&cnt[d & 2047], 1);
        atomicAdd(&cnt[e & 2047], 1);
    }
    for (; i < e1; i += 512)
        atomicAdd(&cnt[__builtin_nontemporal_load(bucketbuf + i) & 2047], 1);
    __syncthreads();
    int base = t * 4;
    int c0 = cnt[base], c1 = cnt[base + 1], c2 = cnt[base + 2], c3 = cnt[base + 3];
    partials[t] = c0 + c1 + c2 + c3;
    __syncthreads();
    if (t == 0) {
        int run = 0;
        for (int k = 0; k < 512; ++k) { int tmp = partials[k]; partials[k] = run; run += tmp; }
    }
    __syncthreads();
    int off = partials[t];
    int cc[4] = {c0, c1, c2, c3};
#pragma unroll
    for (int j = 0; j < 4; ++j) {
        int k = base + j;
        int node = b * 2048 + k;
        if (node < NN) {
            rowStart[node] = e0 + off;
            float di = rsqrtf((float)cc[j] + 1.0f);
            dinv[node] = di;
            p1[node] = x[node] * di;
        }
        off += cc[j];
    }
    if (b == NBUCK - 1 && t == 0) rowStart[NN] = e1;
}

// ---- path A pass 2b: PARALLEL quadrant scatter. 4 WGs per bucket; each owns
//      512 nodes (64KB private output region -> tiny write frontier), scans
//      the full bucket with nt-loads (stream doesn't evict write lines). ----
__global__ __launch_bounds__(512) void scat_kernel(const int* __restrict__ bktStart,
                                                   const int* __restrict__ bucketbuf,
                                                   const int* __restrict__ rowStart,
                                                   int* __restrict__ edgebuf) {
    __shared__ int cur[512];
    int b = blockIdx.x >> 2, p = blockIdx.x & 3;
    int t = threadIdx.x;
    int node = b * 2048 + p * 512 + t;
    cur[t] = (node <= NN) ? rowStart[node] : 0;   // nodes >= NN never referenced
    __syncthreads();
    int e0 = bktStart[b], e1 = bktStart[b + 1];
    for (int i = e0 + t; i < e1; i += 512) {
        int e = __builtin_nontemporal_load(bucketbuf + i);
        int loc = e & 2047;
        if ((loc >> 9) == p) {
            int pos = atomicAdd(&cur[loc & 511], 1);
            edgebuf[pos] = e >> 11;   // plain src, grouped per node
        }
    }
}

// ---- path B pass 2 (fallback): within-bin counting sort, as R9 ----
__global__ __launch_bounds__(256) void sortbin_kernel(const int* __restrict__ binStart,
                                                      int* __restrict__ edgebuf,
                                                      const float* __restrict__ x,
                                                      float* __restrict__ dinv,
                                                      float* __restrict__ p1,
                                                      int* __restrict__ rowStart) {
    __shared__ int stage[CAP];
    __shared__ int cnt[256];
    __shared__ int pref[256];
    __shared__ int cur[256];
    int b = blockIdx.x, t = threadIdx.x;
    cnt[t] = 0;
    __syncthreads();
    int e0 = binStart[b], e1 = binStart[b + 1];
    int n = e1 - e0;
    if (n > CAP) n = CAP;
    for (int i = t; i < n; i += 256) {
        int e = edgebuf[e0 + i];
        stage[i] = e;
        atomicAdd(&cnt[e & 255], 1);
    }
    __syncthreads();
    if (t == 0) {
        int run = 0;
        for (int i = 0; i < 256; ++i) { pref[i] = run; run += cnt[i]; }
    }
    __syncthreads();
    cur[t] = pref[t];
    int node = b * 256 + t;
    if (node < NN) {
        rowStart[node] = e0 + pref[t];
        float di = rsqrtf((float)cnt[t] + 1.0f);
        dinv[node] = di;
        p1[node] = x[node] * di;
    }
    if (b == NBIN - 1 && t == 0) rowStart[NN] = binStart[NBIN];
    __syncthreads();
    for (int i = t; i < n; i += 256) {
        int e = stage[i];
        int pos = e0 + atomicAdd(&cur[e & 255], 1);
        edgebuf[pos] = e >> 8;
    }
}

// ---- layer 1: per-node register gather of p1 (f32), ILP-8 -> p2h (f16x4) ----
__global__ __launch_bounds__(256) void agg1_kernel(const int* __restrict__ rowStart,
                                                   const int* __restrict__ edgebuf,
                                                   const float* __restrict__ p1,
                                                   const float* __restrict__ dinv,
                                                   const float* __restrict__ W1,
                                                   const float* __restrict__ b1,
                                                   const float* __restrict__ W2,
                                                   vhalf4* __restrict__ p2h) {
    int node = blockIdx.x * blockDim.x + threadIdx.x;
    if (node >= NN) return;
    int r0 = rowStart[node], r1 = rowStart[node + 1];
    float s0 = 0.f, s1 = 0.f, s2 = 0.f, s3 = 0.f;
    float s4 = 0.f, s5 = 0.f, s6 = 0.f, s7 = 0.f;
    int k = r0;
    for (; k + 8 <= r1; k += 8) {
        int a = edgebuf[k],     b = edgebuf[k + 1];
        int c = edgebuf[k + 2], d = edgebuf[k + 3];
        int e = edgebuf[k + 4], f = edgebuf[k + 5];
        int g = edgebuf[k + 6], h = edgebuf[k + 7];
        s0 += p1[a]; s1 += p1[b]; s2 += p1[c]; s3 += p1[d];
        s4 += p1[e]; s5 += p1[f]; s6 += p1[g]; s7 += p1[h];
    }
    for (; k < r1; ++k) s0 += p1[edgebuf[k]];
    float acc = ((s0 + s1) + (s2 + s3)) + ((s4 + s5) + (s6 + s7));
    float di = dinv[node];
    float t = di * (acc + p1[node]);   // norm-agg + self-loop
    float h1[4];
#pragma unroll
    for (int f2 = 0; f2 < 4; ++f2) h1[f2] = tanhf(t * W1[f2] + b1[f2]);
    vhalf4 g;
    g.x = (_Float16)(di * (h1[0]*W2[0] + h1[1]*W2[4] + h1[2]*W2[8]  + h1[3]*W2[12]));
    g.y = (_Float16)(di * (h1[0]*W2[1] + h1[1]*W2[5] + h1[2]*W2[9]  + h1[3]*W2[13]));
    g.z = (_Float16)(di * (h1[0]*W2[2] + h1[1]*W2[6] + h1[2]*W2[10] + h1[3]*W2[14]));
    g.w = (_Float16)(di * (h1[0]*W2[3] + h1[1]*W2[7] + h1[2]*W2[11] + h1[3]*W2[15]));
    p2h[node] = g;
}

// ---- layer 2: per-node register gather of p2h (f16x4, 4MB table), ILP-8 ----
__global__ __launch_bounds__(256) void agg2_kernel(const int* __restrict__ rowStart,
                                                   const int* __restrict__ edgebuf,
                                                   const vhalf4* __restrict__ p2h,
                                                   const float* __restrict__ dinv,
                                                   const float* __restrict__ b2,
                                                   const float* __restrict__ W3,
                                                   vhalf2* __restrict__ p3h) {
    int node = blockIdx.x * blockDim.x + threadIdx.x;
    if (node >= NN) return;
    int r0 = rowStart[node], r1 = rowStart[node + 1];
    vfloat4 sA = {0.f, 0.f, 0.f, 0.f};
    vfloat4 sB = {0.f, 0.f, 0.f, 0.f};
    vfloat4 sC = {0.f, 0.f, 0.f, 0.f};
    vfloat4 sD = {0.f, 0.f, 0.f, 0.f};
    int k = r0;
    for (; k + 8 <= r1; k += 8) {
        int a = edgebuf[k],     b = edgebuf[k + 1];
        int c = edgebuf[k + 2], d = edgebuf[k + 3];
        int e = edgebuf[k + 4], f = edgebuf[k + 5];
        int g = edgebuf[k + 6], h = edgebuf[k + 7];
        vhalf4 qa = p2h[a], qb = p2h[b], qc = p2h[c], qd = p2h[d];
        vhalf4 qe = p2h[e], qf = p2h[f], qg = p2h[g], qh = p2h[h];
        sA.x += (float)qa.x + (float)qb.x; sB.x += (float)qc.x + (float)qd.x;
        sA.y += (float)qa.y + (float)qb.y; sB.y += (float)qc.y + (float)qd.y;
        sA.z += (float)qa.z + (float)qb.z; sB.z += (float)qc.z + (float)qd.z;
        sA.w += (float)qa.w + (float)qb.w; sB.w += (float)qc.w + (float)qd.w;
        sC.x += (float)qe.x + (float)qf.x; sD.x += (float)qg.x + (float)qh.x;
        sC.y += (float)qe.y + (float)qf.y; sD.y += (float)qg.y + (float)qh.y;
        sC.z += (float)qe.z + (float)qf.z; sD.z += (float)qg.z + (float)qh.z;
        sC.w += (float)qe.w + (float)qf.w; sD.w += (float)qg.w + (float)qh.w;
    }
    for (; k < r1; ++k) {
        vhalf4 q = p2h[edgebuf[k]];
        sA.x += (float)q.x; sA.y += (float)q.y; sA.z += (float)q.z; sA.w += (float)q.w;
    }
    float di = dinv[node];
    vhalf4 pw = p2h[node];
    float h2[4];
    h2[0] = tanhf(di * (sA.x + sB.x + sC.x + sD.x + (float)pw.x) + b2[0]);
    h2[1] = tanhf(di * (sA.y + sB.y + sC.y + sD.y + (float)pw.y) + b2[1]);
    h2[2] = tanhf(di * (sA.z + sB.z + sC.z + sD.z + (float)pw.z) + b2[2]);
    h2[3] = tanhf(di * (sA.w + sB.w + sC.w + sD.w + (float)pw.w) + b2[3]);
    vhalf2 o;
    o.x = (_Float16)(di * (h2[0]*W3[0] + h2[1]*W3[2] + h2[2]*W3[4] + h2[3]*W3[6]));
    o.y = (_Float16)(di * (h2[0]*W3[1] + h2[1]*W3[3] + h2[2]*W3[5] + h2[3]*W3[7]));
    p3h[node] = o;
}

// ---- layer 3: per-node register gather of p3h (f16x2, 2MB table), ILP-8 ----
__global__ __launch_bounds__(256) void agg3_kernel(const int* __restrict__ rowStart,
                                                   const int* __restrict__ edgebuf,
                                                   const vhalf2* __restrict__ p3h,
                                                   const float* __restrict__ dinv,
                                                   const float* __restrict__ b3,
                                                   const float* __restrict__ Wc,
                                                   const float* __restrict__ bc,
                                                   float* __restrict__ out) {
    int node = blockIdx.x * blockDim.x + threadIdx.x;
    if (node >= NN) return;
    int r0 = rowStart[node], r1 = rowStart[node + 1];
    float ax = 0.f, ay = 0.f, bx = 0.f, by = 0.f;
    float cx = 0.f, cy = 0.f, dx = 0.f, dy = 0.f;
    int k = r0;
    for (; k + 8 <= r1; k += 8) {
        int a = edgebuf[k],     b = edgebuf[k + 1];
        int c = edgebuf[k + 2], d = edgebuf[k + 3];
        int e = edgebuf[k + 4], f = edgebuf[k + 5];
        int g = edgebuf[k + 6], h = edgebuf[k + 7];
        vhalf2 qa = p3h[a], qb = p3h[b], qc = p3h[c], qd = p3h[d];
        vhalf2 qe = p3h[e], qf = p3h[f], qg = p3h[g], qh = p3h[h];
        ax += (float)qa.x + (float)qb.x; bx += (float)qc.x + (float)qd.x;
        ay += (float)qa.y + (float)qb.y; by += (float)qc.y + (float)qd.y;
        cx += (float)qe.x + (float)qf.x; dx += (float)qg.x + (float)qh.x;
        cy += (float)qe.y + (float)qf.y; dy += (float)qg.y + (float)qh.y;
    }
    for (; k < r1; ++k) {
        vhalf2 q = p3h[edgebuf[k]];
        ax += (float)q.x; ay += (float)q.y;
    }
    float di = dinv[node];
    vhalf2 pw = p3h[node];
    float h0 = tanhf(di * (ax + bx + cx + dx + (float)pw.x) + b3[0]);
    float h1 = tanhf(di * (ay + by + cy + dy + (float)pw.y) + b3[1]);
    __builtin_nontemporal_store(h0 * Wc[0] + h1 * Wc[1] + bc[0], out + node);
    vfloat2 hh; hh.x = h0; hh.y = h1;
    __builtin_nontemporal_store(hh, (vfloat2*)(out + NN) + node);
}

// ============================ launch ============================

extern "C" void kernel_launch(void* const* d_in, const int* in_sizes, int n_in,
                              void* d_out, int out_size, void* d_ws, size_t ws_size,
                              hipStream_t stream) {
    const float* x   = (const float*)d_in[0];
    const int*   ei  = (const int*)d_in[1];
    const float* W1  = (const float*)d_in[2];
    const float* b1  = (const float*)d_in[3];
    const float* W2  = (const float*)d_in[4];
    const float* b2  = (const float*)d_in[5];
    const float* W3  = (const float*)d_in[6];
    const float* b3  = (const float*)d_in[7];
    const float* Wc  = (const float*)d_in[8];
    const float* bc  = (const float*)d_in[9];
    float* out = (float*)d_out;
    float* ws  = (float*)d_ws;

    const int* src = ei;
    const int* dst = ei + NE;

    float*  dinv     = ws;
    float*  p1       = ws + (size_t)NN;
    vhalf4* p2h      = (vhalf4*)(ws + 2ull * NN);
    vhalf2* p3h      = (vhalf2*)(ws + 4ull * NN);
    int*    rowStart = (int*)(ws + 5ull * NN);
    int*    tail     = (int*)(ws + 6ull * NN + 1);   // path-specific region

    const int B = 256;
    const int aggGrid = (NN + B - 1) / B;            // 1954

    // path A needs: 6NN+1 + NWGA*NBUCK + NBUCK + (NBUCK+1) + 2*NE units (~141MB)
    const size_t needA = (6ull * NN + 1 + (size_t)NWGA * NBUCK + NBUCK + NBUCK + 1
                          + 2ull * NE) * 4ull;

    if (ws_size >= needA) {
        // ---------- path A: two-level ----------
        int* wgHist    = tail;
        int* bktTotal  = wgHist + (size_t)NWGA * NBUCK;
        int* bktStart  = bktTotal + NBUCK;
        int* bucketbuf = bktStart + NBUCK + 1;
        int* edgebuf   = bucketbuf + (size_t)NE;

        hipLaunchKernelGGL(hist_kernel, dim3(NWGA), dim3(B), 0, stream,
                           dst, wgHist, 11, NBUCK, CHUNKA4);
        hipLaunchKernelGGL(scanbins_kernel, dim3(NBUCK), dim3(B), 0, stream,
                           wgHist, bktTotal, NWGA, NBUCK);
        hipLaunchKernelGGL(scantotal_kernel, dim3(1), dim3(512), 0, stream,
                           bktTotal, bktStart, NBUCK);
        hipLaunchKernelGGL(reorder_kernel, dim3(NWGA), dim3(B), 0, stream,
                           src, dst, wgHist, bktStart, bucketbuf, 11, NBUCK, CHUNKA4);
        hipLaunchKernelGGL(count_kernel, dim3(NBUCK), dim3(512), 0, stream,
                           bktStart, bucketbuf, x, dinv, p1, rowStart);
        hipLaunchKernelGGL(scat_kernel, dim3(NBUCK * 4), dim3(512), 0, stream,
                           bktStart, bucketbuf, rowStart, edgebuf);
        hipLaunchKernelGGL(agg1_kernel, dim3(aggGrid), dim3(B), 0, stream,
                           rowStart, edgebuf, p1, dinv, W1, b1, W2, p2h);
        hipLaunchKernelGGL(agg2_kernel, dim3(aggGrid), dim3(B), 0, stream,
                           rowStart, edgebuf, p2h, dinv, b2, W3, p3h);
        hipLaunchKernelGGL(agg3_kernel, dim3(aggGrid), dim3(B), 0, stream,
                           rowStart, edgebuf, p3h, dinv, b3, Wc, bc, out);
    } else {
        // ---------- path B: fallback (R9 single-level) ----------
        int* wgHist   = tail;
        int* binTotal = wgHist + (size_t)NWGB * NBIN;
        int* binStart = binTotal + NBIN;
        int* edgebuf  = binStart + NBIN + 1;

        hipLaunchKernelGGL(hist_kernel, dim3(NWGB), dim3(B), 0, stream,
                           dst, wgHist, 8, NBIN, CHUNKB4);
        hipLaunchKernelGGL(scanbins_kernel, dim3(NBIN), dim3(B), 0, stream,
                           wgHist, binTotal, NWGB, NBIN);
        hipLaunchKernelGGL(scantotal_kernel, dim3(1), dim3(512), 0, stream,
                           binTotal, binStart, NBIN);
        hipLaunchKernelGGL(reorder_kernel, dim3(NWGB), dim3(B), 0, stream,
                           src, dst, wgHist, binStart, edgebuf, 8, NBIN, CHUNKB4);
        hipLaunchKernelGGL(sortbin_kernel, dim3(NBIN), dim3(B), 0, stream,
                           binStart, edgebuf, x, dinv, p1, rowStart);
        hipLaunchKernelGGL(agg1_kernel, dim3(aggGrid), dim3(B), 0, stream,
                           rowStart, edgebuf, p1, dinv, W1, b1, W2, p2h);
        hipLaunchKernelGGL(agg2_kernel, dim3(aggGrid), dim3(B), 0, stream,
                           rowStart, edgebuf, p2h, dinv, b2, W3, p3h);
        hipLaunchKernelGGL(agg3_kernel, dim3(aggGrid), dim3(B), 0, stream,
                           rowStart, edgebuf, p3h, dinv, b3, Wc, bc, out);
    }
}

// Round 15
// 682.232 us; speedup vs baseline: 1.3562x; 1.3562x over previous
//
#include <hip/hip_runtime.h>

#define NN   500000
#define NE   16000000
#define NBIN 1954        // ceil(NN/256); node bin = node >> 8 (path B)

// ---- path A: two-level partition (needs ~141 MB ws, proven present R11-R14) ----
#define NBUCK   245      // ceil(NN/2048); bucket = dst >> 11
#define NWGA    1000
#define CHUNKA4 4000     // (NE/NWGA)/4
// ---- path B: fallback = R9 single-level (91.6 MB ws) ----
#define NWGB    2000
#define CHUNKB4 2000
#define CAP     14336

typedef int      vint4   __attribute__((ext_vector_type(4)));
typedef float    vfloat4 __attribute__((ext_vector_type(4)));
typedef float    vfloat2 __attribute__((ext_vector_type(2)));
typedef _Float16 vhalf4  __attribute__((ext_vector_type(4)));
typedef _Float16 vhalf2  __attribute__((ext_vector_type(2)));

// ---- generic per-WG histogram over dst>>shift (LDS atomics only) ----
__global__ __launch_bounds__(256) void hist_kernel(const int* __restrict__ dst,
                                                   int* __restrict__ wgHist,
                                                   int shift, int nbin, int chunk4) {
    __shared__ int hist[NBIN];
    for (int i = threadIdx.x; i < nbin; i += 256) hist[i] = 0;
    __syncthreads();
    const vint4* d4 = (const vint4*)(dst + (size_t)blockIdx.x * chunk4 * 4);
    for (int i = threadIdx.x; i < chunk4; i += 256) {
        vint4 d = __builtin_nontemporal_load(d4 + i);
        atomicAdd(&hist[d.x >> shift], 1);
        atomicAdd(&hist[d.y >> shift], 1);
        atomicAdd(&hist[d.z >> shift], 1);
        atomicAdd(&hist[d.w >> shift], 1);
    }
    __syncthreads();
    int* row = wgHist + (size_t)blockIdx.x * nbin;
    for (int i = threadIdx.x; i < nbin; i += 256) row[i] = hist[i];
}

// ---- per-bin exclusive scan across WGs: one block per bin ----
__global__ __launch_bounds__(256) void scanbins_kernel(int* __restrict__ wgHist,
                                                       int* __restrict__ binTotal,
                                                       int nwg, int nbin) {
    __shared__ int partials[256];
    int bin = blockIdx.x;
    int t = threadIdx.x;
    int per = (nwg + 255) / 256;
    int w0 = t * per;
    int w1 = w0 + per; if (w1 > nwg) w1 = nwg;
    int s = 0;
    for (int w = w0; w < w1; ++w) s += wgHist[(size_t)w * nbin + bin];
    partials[t] = s;
    __syncthreads();
    if (t == 0) {
        int run = 0;
        for (int i = 0; i < 256; ++i) { int tmp = partials[i]; partials[i] = run; run += tmp; }
        binTotal[bin] = run;
    }
    __syncthreads();
    int off = partials[t];
    for (int w = w0; w < w1; ++w) {
        size_t idx = (size_t)w * nbin + bin;
        int v = wgHist[idx];
        wgHist[idx] = off;
        off += v;
    }
}

// ---- exclusive scan over bins (nbin <= 2048) ----
__global__ void scantotal_kernel(const int* __restrict__ binTotal, int* __restrict__ binStart,
                                 int nbin) {
    __shared__ int partials[512];
    int t = threadIdx.x;
    int base = t * 4;
    int v[4]; int s = 0;
#pragma unroll
    for (int j = 0; j < 4; ++j) {
        int b = base + j;
        v[j] = (b < nbin) ? binTotal[b] : 0;
        s += v[j];
    }
    partials[t] = s;
    __syncthreads();
    if (t == 0) {
        int run = 0;
        for (int i = 0; i < 512; ++i) { int tmp = partials[i]; partials[i] = run; run += tmp; }
        binStart[nbin] = run;  // == NE
    }
    __syncthreads();
    int off = partials[t];
#pragma unroll
    for (int j = 0; j < 4; ++j) {
        int b = base + j;
        if (b < nbin) binStart[b] = off;
        off += v[j];
    }
}

// ---- generic scatter into bins; pack (src<<shift)|(dst&mask); normal stores ----
__global__ __launch_bounds__(256) void reorder_kernel(const int* __restrict__ src,
                                                      const int* __restrict__ dst,
                                                      const int* __restrict__ wgHist,
                                                      const int* __restrict__ binStart,
                                                      int* __restrict__ outbuf,
                                                      int shift, int nbin, int chunk4) {
    __shared__ int cur[NBIN];
    const int* row = wgHist + (size_t)blockIdx.x * nbin;
    for (int i = threadIdx.x; i < nbin; i += 256) cur[i] = binStart[i] + row[i];
    __syncthreads();
    const int mask = (1 << shift) - 1;
    const vint4* s4 = (const vint4*)(src + (size_t)blockIdx.x * chunk4 * 4);
    const vint4* d4 = (const vint4*)(dst + (size_t)blockIdx.x * chunk4 * 4);
    for (int i = threadIdx.x; i < chunk4; i += 256) {
        vint4 s = __builtin_nontemporal_load(s4 + i);
        vint4 d = __builtin_nontemporal_load(d4 + i);
        int ss[4] = {s.x, s.y, s.z, s.w};
        int dd[4] = {d.x, d.y, d.z, d.w};
#pragma unroll
        for (int k = 0; k < 4; ++k) {
            int pos = atomicAdd(&cur[dd[k] >> shift], 1);
            outbuf[pos] = (ss[k] << shift) | (dd[k] & mask);
        }
    }
}

// ---- path A pass 2a: per-bucket counts -> rowStart/dinv/p1 (no scatter).
//      Must run over ALL buckets before scat2 (p1[src] is cross-bucket). ----
__global__ __launch_bounds__(512) void count_kernel(const int* __restrict__ bktStart,
                                                    const int* __restrict__ bucketbuf,
                                                    const float* __restrict__ x,
                                                    float* __restrict__ dinv,
                                                    float* __restrict__ p1,
                                                    int* __restrict__ rowStart) {
    __shared__ int cnt[2048];
    __shared__ int partials[512];
    int b = blockIdx.x, t = threadIdx.x;
    for (int k = t; k < 2048; k += 512) cnt[k] = 0;
    __syncthreads();
    int e0 = bktStart[b], e1 = bktStart[b + 1];
    int i = e0 + t;
    for (; i + 3 * 512 < e1; i += 4 * 512) {
        int a = bucketbuf[i];
        int c = bucketbuf[i + 512];
        int d = bucketbuf[i + 1024];
        int e = bucketbuf[i + 1536];
        atomicAdd(&cnt[a & 2047], 1);
        atomicAdd(&cnt[c & 2047], 1);
        atomicAdd(&cnt[d & 2047], 1);
        atomicAdd(&cnt[e & 2047], 1);
    }
    for (; i < e1; i += 512)
        atomicAdd(&cnt[bucketbuf[i] & 2047], 1);
    __syncthreads();
    int base = t * 4;
    int c0 = cnt[base], c1 = cnt[base + 1], c2 = cnt[base + 2], c3 = cnt[base + 3];
    partials[t] = c0 + c1 + c2 + c3;
    __syncthreads();
    if (t == 0) {
        int run = 0;
        for (int k = 0; k < 512; ++k) { int tmp = partials[k]; partials[k] = run; run += tmp; }
    }
    __syncthreads();
    int off = partials[t];
    int cc[4] = {c0, c1, c2, c3};
#pragma unroll
    for (int j = 0; j < 4; ++j) {
        int k = base + j;
        int node = b * 2048 + k;
        if (node < NN) {
            rowStart[node] = e0 + off;
            float di = rsqrtf((float)cc[j] + 1.0f);
            dinv[node] = di;
            p1[node] = x[node] * di;
        }
        off += cc[j];
    }
    if (b == NBUCK - 1 && t == 0) rowStart[NN] = e1;
}

// ---- path A pass 2b: scatter -> per-node CSR, FUSED with layer-1 agg +
//      epilogue (saves agg1_kernel's full 64MB edgebuf re-read + gathers).
//      Scatter structure identical to R11's proven csr (210us). ----
__global__ __launch_bounds__(512) void scat2_kernel(const int* __restrict__ bktStart,
                                                    const int* __restrict__ bucketbuf,
                                                    const int* __restrict__ rowStart,
                                                    const float* __restrict__ p1,
                                                    const float* __restrict__ dinv,
                                                    const float* __restrict__ W1,
                                                    const float* __restrict__ b1,
                                                    const float* __restrict__ W2,
                                                    int* __restrict__ edgebuf,
                                                    vhalf4* __restrict__ p2h) {
    __shared__ int   cur[2048];
    __shared__ float acc[2048];
    int b = blockIdx.x, t = threadIdx.x;
    for (int k = t; k < 2048; k += 512) {
        int node = b * 2048 + k;
        cur[k] = (node < NN) ? rowStart[node] : 0;
        acc[k] = 0.0f;
    }
    __syncthreads();
    int e0 = bktStart[b], e1 = bktStart[b + 1];
    int i = e0 + t;
    for (; i + 512 < e1; i += 1024) {
        int ea = bucketbuf[i];
        int eb = bucketbuf[i + 512];
        int la = ea & 2047, sa = ea >> 11;
        int lb = eb & 2047, sb = eb >> 11;
        float va = p1[sa];
        float vb = p1[sb];
        int pa = atomicAdd(&cur[la], 1);
        int pb = atomicAdd(&cur[lb], 1);
        edgebuf[pa] = sa;
        edgebuf[pb] = sb;
        atomicAdd(&acc[la], va);
        atomicAdd(&acc[lb], vb);
    }
    for (; i < e1; i += 512) {
        int e = bucketbuf[i];
        int loc = e & 2047, srcn = e >> 11;
        int pos = atomicAdd(&cur[loc], 1);
        edgebuf[pos] = srcn;
        atomicAdd(&acc[loc], p1[srcn]);
    }
    __syncthreads();
    // fused layer-1 epilogue: h1 = tanh(W1*t + b1); p2h = di * (h1 @ W2)
    for (int k = t; k < 2048; k += 512) {
        int node = b * 2048 + k;
        if (node < NN) {
            float di = dinv[node];
            float tt = di * (acc[k] + p1[node]);   // norm-agg + self-loop
            float h1[4];
#pragma unroll
            for (int f = 0; f < 4; ++f) h1[f] = tanhf(tt * W1[f] + b1[f]);
            vhalf4 g;
            g.x = (_Float16)(di * (h1[0]*W2[0] + h1[1]*W2[4] + h1[2]*W2[8]  + h1[3]*W2[12]));
            g.y = (_Float16)(di * (h1[0]*W2[1] + h1[1]*W2[5] + h1[2]*W2[9]  + h1[3]*W2[13]));
            g.z = (_Float16)(di * (h1[0]*W2[2] + h1[1]*W2[6] + h1[2]*W2[10] + h1[3]*W2[14]));
            g.w = (_Float16)(di * (h1[0]*W2[3] + h1[1]*W2[7] + h1[2]*W2[11] + h1[3]*W2[15]));
            p2h[node] = g;
        }
    }
}

// ---- path B pass 2 (fallback): within-bin counting sort, as R9 ----
__global__ __launch_bounds__(256) void sortbin_kernel(const int* __restrict__ binStart,
                                                      int* __restrict__ edgebuf,
                                                      const float* __restrict__ x,
                                                      float* __restrict__ dinv,
                                                      float* __restrict__ p1,
                                                      int* __restrict__ rowStart) {
    __shared__ int stage[CAP];
    __shared__ int cnt[256];
    __shared__ int pref[256];
    __shared__ int cur[256];
    int b = blockIdx.x, t = threadIdx.x;
    cnt[t] = 0;
    __syncthreads();
    int e0 = binStart[b], e1 = binStart[b + 1];
    int n = e1 - e0;
    if (n > CAP) n = CAP;
    for (int i = t; i < n; i += 256) {
        int e = edgebuf[e0 + i];
        stage[i] = e;
        atomicAdd(&cnt[e & 255], 1);
    }
    __syncthreads();
    if (t == 0) {
        int run = 0;
        for (int i = 0; i < 256; ++i) { pref[i] = run; run += cnt[i]; }
    }
    __syncthreads();
    cur[t] = pref[t];
    int node = b * 256 + t;
    if (node < NN) {
        rowStart[node] = e0 + pref[t];
        float di = rsqrtf((float)cnt[t] + 1.0f);
        dinv[node] = di;
        p1[node] = x[node] * di;
    }
    if (b == NBIN - 1 && t == 0) rowStart[NN] = binStart[NBIN];
    __syncthreads();
    for (int i = t; i < n; i += 256) {
        int e = stage[i];
        int pos = e0 + atomicAdd(&cur[e & 255], 1);
        edgebuf[pos] = e >> 8;
    }
}

// ---- layer 1 (path B only): per-node register gather of p1 -> p2h ----
__global__ __launch_bounds__(256) void agg1_kernel(const int* __restrict__ rowStart,
                                                   const int* __restrict__ edgebuf,
                                                   const float* __restrict__ p1,
                                                   const float* __restrict__ dinv,
                                                   const float* __restrict__ W1,
                                                   const float* __restrict__ b1,
                                                   const float* __restrict__ W2,
                                                   vhalf4* __restrict__ p2h) {
    int node = blockIdx.x * blockDim.x + threadIdx.x;
    if (node >= NN) return;
    int r0 = rowStart[node], r1 = rowStart[node + 1];
    float s0 = 0.f, s1 = 0.f, s2 = 0.f, s3 = 0.f;
    float s4 = 0.f, s5 = 0.f, s6 = 0.f, s7 = 0.f;
    int k = r0;
    for (; k + 8 <= r1; k += 8) {
        int a = edgebuf[k],     b = edgebuf[k + 1];
        int c = edgebuf[k + 2], d = edgebuf[k + 3];
        int e = edgebuf[k + 4], f = edgebuf[k + 5];
        int g = edgebuf[k + 6], h = edgebuf[k + 7];
        s0 += p1[a]; s1 += p1[b]; s2 += p1[c]; s3 += p1[d];
        s4 += p1[e]; s5 += p1[f]; s6 += p1[g]; s7 += p1[h];
    }
    for (; k < r1; ++k) s0 += p1[edgebuf[k]];
    float acc = ((s0 + s1) + (s2 + s3)) + ((s4 + s5) + (s6 + s7));
    float di = dinv[node];
    float t = di * (acc + p1[node]);
    float h1[4];
#pragma unroll
    for (int f2 = 0; f2 < 4; ++f2) h1[f2] = tanhf(t * W1[f2] + b1[f2]);
    vhalf4 g;
    g.x = (_Float16)(di * (h1[0]*W2[0] + h1[1]*W2[4] + h1[2]*W2[8]  + h1[3]*W2[12]));
    g.y = (_Float16)(di * (h1[0]*W2[1] + h1[1]*W2[5] + h1[2]*W2[9]  + h1[3]*W2[13]));
    g.z = (_Float16)(di * (h1[0]*W2[2] + h1[1]*W2[6] + h1[2]*W2[10] + h1[3]*W2[14]));
    g.w = (_Float16)(di * (h1[0]*W2[3] + h1[1]*W2[7] + h1[2]*W2[11] + h1[3]*W2[15]));
    p2h[node] = g;
}

// ---- layer 2: per-node register gather of p2h (f16x4, 4MB table), ILP-8 ----
__global__ __launch_bounds__(256) void agg2_kernel(const int* __restrict__ rowStart,
                                                   const int* __restrict__ edgebuf,
                                                   const vhalf4* __restrict__ p2h,
                                                   const float* __restrict__ dinv,
                                                   const float* __restrict__ b2,
                                                   const float* __restrict__ W3,
                                                   vhalf2* __restrict__ p3h) {
    int node = blockIdx.x * blockDim.x + threadIdx.x;
    if (node >= NN) return;
    int r0 = rowStart[node], r1 = rowStart[node + 1];
    vfloat4 sA = {0.f, 0.f, 0.f, 0.f};
    vfloat4 sB = {0.f, 0.f, 0.f, 0.f};
    vfloat4 sC = {0.f, 0.f, 0.f, 0.f};
    vfloat4 sD = {0.f, 0.f, 0.f, 0.f};
    int k = r0;
    for (; k + 8 <= r1; k += 8) {
        int a = edgebuf[k],     b = edgebuf[k + 1];
        int c = edgebuf[k + 2], d = edgebuf[k + 3];
        int e = edgebuf[k + 4], f = edgebuf[k + 5];
        int g = edgebuf[k + 6], h = edgebuf[k + 7];
        vhalf4 qa = p2h[a], qb = p2h[b], qc = p2h[c], qd = p2h[d];
        vhalf4 qe = p2h[e], qf = p2h[f], qg = p2h[g], qh = p2h[h];
        sA.x += (float)qa.x + (float)qb.x; sB.x += (float)qc.x + (float)qd.x;
        sA.y += (float)qa.y + (float)qb.y; sB.y += (float)qc.y + (float)qd.y;
        sA.z += (float)qa.z + (float)qb.z; sB.z += (float)qc.z + (float)qd.z;
        sA.w += (float)qa.w + (float)qb.w; sB.w += (float)qc.w + (float)qd.w;
        sC.x += (float)qe.x + (float)qf.x; sD.x += (float)qg.x + (float)qh.x;
        sC.y += (float)qe.y + (float)qf.y; sD.y += (float)qg.y + (float)qh.y;
        sC.z += (float)qe.z + (float)qf.z; sD.z += (float)qg.z + (float)qh.z;
        sC.w += (float)qe.w + (float)qf.w; sD.w += (float)qg.w + (float)qh.w;
    }
    for (; k < r1; ++k) {
        vhalf4 q = p2h[edgebuf[k]];
        sA.x += (float)q.x; sA.y += (float)q.y; sA.z += (float)q.z; sA.w += (float)q.w;
    }
    float di = dinv[node];
    vhalf4 pw = p2h[node];
    float h2[4];
    h2[0] = tanhf(di * (sA.x + sB.x + sC.x + sD.x + (float)pw.x) + b2[0]);
    h2[1] = tanhf(di * (sA.y + sB.y + sC.y + sD.y + (float)pw.y) + b2[1]);
    h2[2] = tanhf(di * (sA.z + sB.z + sC.z + sD.z + (float)pw.z) + b2[2]);
    h2[3] = tanhf(di * (sA.w + sB.w + sC.w + sD.w + (float)pw.w) + b2[3]);
    vhalf2 o;
    o.x = (_Float16)(di * (h2[0]*W3[0] + h2[1]*W3[2] + h2[2]*W3[4] + h2[3]*W3[6]));
    o.y = (_Float16)(di * (h2[0]*W3[1] + h2[1]*W3[3] + h2[2]*W3[5] + h2[3]*W3[7]));
    p3h[node] = o;
}

// ---- layer 3: per-node register gather of p3h (f16x2, 2MB table), ILP-8 ----
__global__ __launch_bounds__(256) void agg3_kernel(const int* __restrict__ rowStart,
                                                   const int* __restrict__ edgebuf,
                                                   const vhalf2* __restrict__ p3h,
                                                   const float* __restrict__ dinv,
                                                   const float* __restrict__ b3,
                                                   const float* __restrict__ Wc,
                                                   const float* __restrict__ bc,
                                                   float* __restrict__ out) {
    int node = blockIdx.x * blockDim.x + threadIdx.x;
    if (node >= NN) return;
    int r0 = rowStart[node], r1 = rowStart[node + 1];
    float ax = 0.f, ay = 0.f, bx = 0.f, by = 0.f;
    float cx = 0.f, cy = 0.f, dx = 0.f, dy = 0.f;
    int k = r0;
    for (; k + 8 <= r1; k += 8) {
        int a = edgebuf[k],     b = edgebuf[k + 1];
        int c = edgebuf[k + 2], d = edgebuf[k + 3];
        int e = edgebuf[k + 4], f = edgebuf[k + 5];
        int g = edgebuf[k + 6], h = edgebuf[k + 7];
        vhalf2 qa = p3h[a], qb = p3h[b], qc = p3h[c], qd = p3h[d];
        vhalf2 qe = p3h[e], qf = p3h[f], qg = p3h[g], qh = p3h[h];
        ax += (float)qa.x + (float)qb.x; bx += (float)qc.x + (float)qd.x;
        ay += (float)qa.y + (float)qb.y; by += (float)qc.y + (float)qd.y;
        cx += (float)qe.x + (float)qf.x; dx += (float)qg.x + (float)qh.x;
        cy += (float)qe.y + (float)qf.y; dy += (float)qg.y + (float)qh.y;
    }
    for (; k < r1; ++k) {
        vhalf2 q = p3h[edgebuf[k]];
        ax += (float)q.x; ay += (float)q.y;
    }
    float di = dinv[node];
    vhalf2 pw = p3h[node];
    float h0 = tanhf(di * (ax + bx + cx + dx + (float)pw.x) + b3[0]);
    float h1 = tanhf(di * (ay + by + cy + dy + (float)pw.y) + b3[1]);
    __builtin_nontemporal_store(h0 * Wc[0] + h1 * Wc[1] + bc[0], out + node);
    vfloat2 hh; hh.x = h0; hh.y = h1;
    __builtin_nontemporal_store(hh, (vfloat2*)(out + NN) + node);
}

// ============================ launch ============================

extern "C" void kernel_launch(void* const* d_in, const int* in_sizes, int n_in,
                              void* d_out, int out_size, void* d_ws, size_t ws_size,
                              hipStream_t stream) {
    const float* x   = (const float*)d_in[0];
    const int*   ei  = (const int*)d_in[1];
    const float* W1  = (const float*)d_in[2];
    const float* b1  = (const float*)d_in[3];
    const float* W2  = (const float*)d_in[4];
    const float* b2  = (const float*)d_in[5];
    const float* W3  = (const float*)d_in[6];
    const float* b3  = (const float*)d_in[7];
    const float* Wc  = (const float*)d_in[8];
    const float* bc  = (const float*)d_in[9];
    float* out = (float*)d_out;
    float* ws  = (float*)d_ws;

    const int* src = ei;
    const int* dst = ei + NE;

    float*  dinv     = ws;
    float*  p1       = ws + (size_t)NN;
    vhalf4* p2h      = (vhalf4*)(ws + 2ull * NN);
    vhalf2* p3h      = (vhalf2*)(ws + 4ull * NN);
    int*    rowStart = (int*)(ws + 5ull * NN);
    int*    tail     = (int*)(ws + 6ull * NN + 1);   // path-specific region

    const int B = 256;
    const int aggGrid = (NN + B - 1) / B;            // 1954

    // path A needs: 6NN+1 + NWGA*NBUCK + NBUCK + (NBUCK+1) + 2*NE units (~141MB)
    const size_t needA = (6ull * NN + 1 + (size_t)NWGA * NBUCK + NBUCK + NBUCK + 1
                          + 2ull * NE) * 4ull;

    if (ws_size >= needA) {
        // ---------- path A: two-level, agg1 fused into scatter ----------
        int* wgHist    = tail;
        int* bktTotal  = wgHist + (size_t)NWGA * NBUCK;
        int* bktStart  = bktTotal + NBUCK;
        int* bucketbuf = bktStart + NBUCK + 1;
        int* edgebuf   = bucketbuf + (size_t)NE;

        hipLaunchKernelGGL(hist_kernel, dim3(NWGA), dim3(B), 0, stream,
                           dst, wgHist, 11, NBUCK, CHUNKA4);
        hipLaunchKernelGGL(scanbins_kernel, dim3(NBUCK), dim3(B), 0, stream,
                           wgHist, bktTotal, NWGA, NBUCK);
        hipLaunchKernelGGL(scantotal_kernel, dim3(1), dim3(512), 0, stream,
                           bktTotal, bktStart, NBUCK);
        hipLaunchKernelGGL(reorder_kernel, dim3(NWGA), dim3(B), 0, stream,
                           src, dst, wgHist, bktStart, bucketbuf, 11, NBUCK, CHUNKA4);
        hipLaunchKernelGGL(count_kernel, dim3(NBUCK), dim3(512), 0, stream,
                           bktStart, bucketbuf, x, dinv, p1, rowStart);
        hipLaunchKernelGGL(scat2_kernel, dim3(NBUCK), dim3(512), 0, stream,
                           bktStart, bucketbuf, rowStart, p1, dinv, W1, b1, W2,
                           edgebuf, p2h);
        hipLaunchKernelGGL(agg2_kernel, dim3(aggGrid), dim3(B), 0, stream,
                           rowStart, edgebuf, p2h, dinv, b2, W3, p3h);
        hipLaunchKernelGGL(agg3_kernel, dim3(aggGrid), dim3(B), 0, stream,
                           rowStart, edgebuf, p3h, dinv, b3, Wc, bc, out);
    } else {
        // ---------- path B: fallback (R9 single-level) ----------
        int* wgHist   = tail;
        int* binTotal = wgHist + (size_t)NWGB * NBIN;
        int* binStart = binTotal + NBIN;
        int* edgebuf  = binStart + NBIN + 1;

        hipLaunchKernelGGL(hist_kernel, dim3(NWGB), dim3(B), 0, stream,
                           dst, wgHist, 8, NBIN, CHUNKB4);
        hipLaunchKernelGGL(scanbins_kernel, dim3(NBIN), dim3(B), 0, stream,
                           wgHist, binTotal, NWGB, NBIN);
        hipLaunchKernelGGL(scantotal_kernel, dim3(1), dim3(512), 0, stream,
                           binTotal, binStart, NBIN);
        hipLaunchKernelGGL(reorder_kernel, dim3(NWGB), dim3(B), 0, stream,
                           src, dst, wgHist, binStart, edgebuf, 8, NBIN, CHUNKB4);
        hipLaunchKernelGGL(sortbin_kernel, dim3(NBIN), dim3(B), 0, stream,
                           binStart, edgebuf, x, dinv, p1, rowStart);
        hipLaunchKernelGGL(agg1_kernel, dim3(aggGrid), dim3(B), 0, stream,
                           rowStart, edgebuf, p1, dinv, W1, b1, W2, p2h);
        hipLaunchKernelGGL(agg2_kernel, dim3(aggGrid), dim3(B), 0, stream,
                           rowStart, edgebuf, p2h, dinv, b2, W3, p3h);
        hipLaunchKernelGGL(agg3_kernel, dim3(aggGrid), dim3(B), 0, stream,
                           rowStart, edgebuf, p3h, dinv, b3, Wc, bc, out);
    }
}

// Round 16
// 679.489 us; speedup vs baseline: 1.3617x; 1.0040x over previous
//
#include <hip/hip_runtime.h>

#define NN   500000
#define NE   16000000
#define NBIN 1954        // ceil(NN/256); node bin = node >> 8 (path B)

// ---- path A: two-level partition (needs ~141 MB ws, proven present R11-R15) ----
#define NBUCK   245      // ceil(NN/2048); bucket = dst >> 11
#define NWGA    1000
#define CHUNKA4 4000     // (NE/NWGA)/4
// ---- path B: fallback = R9 single-level (91.6 MB ws) ----
#define NWGB    2000
#define CHUNKB4 2000
#define CAP     14336

typedef int      vint4   __attribute__((ext_vector_type(4)));
typedef float    vfloat4 __attribute__((ext_vector_type(4)));
typedef float    vfloat2 __attribute__((ext_vector_type(2)));
typedef _Float16 vhalf4  __attribute__((ext_vector_type(4)));
typedef _Float16 vhalf2  __attribute__((ext_vector_type(2)));

// ---- generic per-WG histogram over dst>>shift (LDS atomics only) ----
__global__ __launch_bounds__(256) void hist_kernel(const int* __restrict__ dst,
                                                   int* __restrict__ wgHist,
                                                   int shift, int nbin, int chunk4) {
    __shared__ int hist[NBIN];
    for (int i = threadIdx.x; i < nbin; i += 256) hist[i] = 0;
    __syncthreads();
    const vint4* d4 = (const vint4*)(dst + (size_t)blockIdx.x * chunk4 * 4);
    for (int i = threadIdx.x; i < chunk4; i += 256) {
        vint4 d = __builtin_nontemporal_load(d4 + i);
        atomicAdd(&hist[d.x >> shift], 1);
        atomicAdd(&hist[d.y >> shift], 1);
        atomicAdd(&hist[d.z >> shift], 1);
        atomicAdd(&hist[d.w >> shift], 1);
    }
    __syncthreads();
    int* row = wgHist + (size_t)blockIdx.x * nbin;
    for (int i = threadIdx.x; i < nbin; i += 256) row[i] = hist[i];
}

// ---- per-bin exclusive scan across WGs: one block per bin ----
__global__ __launch_bounds__(256) void scanbins_kernel(int* __restrict__ wgHist,
                                                       int* __restrict__ binTotal,
                                                       int nwg, int nbin) {
    __shared__ int partials[256];
    int bin = blockIdx.x;
    int t = threadIdx.x;
    int per = (nwg + 255) / 256;
    int w0 = t * per;
    int w1 = w0 + per; if (w1 > nwg) w1 = nwg;
    int s = 0;
    for (int w = w0; w < w1; ++w) s += wgHist[(size_t)w * nbin + bin];
    partials[t] = s;
    __syncthreads();
    if (t == 0) {
        int run = 0;
        for (int i = 0; i < 256; ++i) { int tmp = partials[i]; partials[i] = run; run += tmp; }
        binTotal[bin] = run;
    }
    __syncthreads();
    int off = partials[t];
    for (int w = w0; w < w1; ++w) {
        size_t idx = (size_t)w * nbin + bin;
        int v = wgHist[idx];
        wgHist[idx] = off;
        off += v;
    }
}

// ---- exclusive scan over bins (nbin <= 2048) ----
__global__ void scantotal_kernel(const int* __restrict__ binTotal, int* __restrict__ binStart,
                                 int nbin) {
    __shared__ int partials[512];
    int t = threadIdx.x;
    int base = t * 4;
    int v[4]; int s = 0;
#pragma unroll
    for (int j = 0; j < 4; ++j) {
        int b = base + j;
        v[j] = (b < nbin) ? binTotal[b] : 0;
        s += v[j];
    }
    partials[t] = s;
    __syncthreads();
    if (t == 0) {
        int run = 0;
        for (int i = 0; i < 512; ++i) { int tmp = partials[i]; partials[i] = run; run += tmp; }
        binStart[nbin] = run;  // == NE
    }
    __syncthreads();
    int off = partials[t];
#pragma unroll
    for (int j = 0; j < 4; ++j) {
        int b = base + j;
        if (b < nbin) binStart[b] = off;
        off += v[j];
    }
}

// ---- generic scatter into bins; pack (src<<shift)|(dst&mask); normal stores ----
__global__ __launch_bounds__(256) void reorder_kernel(const int* __restrict__ src,
                                                      const int* __restrict__ dst,
                                                      const int* __restrict__ wgHist,
                                                      const int* __restrict__ binStart,
                                                      int* __restrict__ outbuf,
                                                      int shift, int nbin, int chunk4) {
    __shared__ int cur[NBIN];
    const int* row = wgHist + (size_t)blockIdx.x * nbin;
    for (int i = threadIdx.x; i < nbin; i += 256) cur[i] = binStart[i] + row[i];
    __syncthreads();
    const int mask = (1 << shift) - 1;
    const vint4* s4 = (const vint4*)(src + (size_t)blockIdx.x * chunk4 * 4);
    const vint4* d4 = (const vint4*)(dst + (size_t)blockIdx.x * chunk4 * 4);
    for (int i = threadIdx.x; i < chunk4; i += 256) {
        vint4 s = __builtin_nontemporal_load(s4 + i);
        vint4 d = __builtin_nontemporal_load(d4 + i);
        int ss[4] = {s.x, s.y, s.z, s.w};
        int dd[4] = {d.x, d.y, d.z, d.w};
#pragma unroll
        for (int k = 0; k < 4; ++k) {
            int pos = atomicAdd(&cur[dd[k] >> shift], 1);
            outbuf[pos] = (ss[k] << shift) | (dd[k] & mask);
        }
    }
}

// ---- path A pass 2a: per-bucket counts -> rowStart/dinv/p1 (1024 thr) ----
__global__ __launch_bounds__(1024) void count_kernel(const int* __restrict__ bktStart,
                                                     const int* __restrict__ bucketbuf,
                                                     const float* __restrict__ x,
                                                     float* __restrict__ dinv,
                                                     float* __restrict__ p1,
                                                     int* __restrict__ rowStart) {
    __shared__ int cnt[2048];
    __shared__ int partials[1024];
    int b = blockIdx.x, t = threadIdx.x;
    for (int k = t; k < 2048; k += 1024) cnt[k] = 0;
    __syncthreads();
    int e0 = bktStart[b], e1 = bktStart[b + 1];
    int i = e0 + t;
    for (; i + 3 * 1024 < e1; i += 4 * 1024) {
        int a = bucketbuf[i];
        int c = bucketbuf[i + 1024];
        int d = bucketbuf[i + 2048];
        int e = bucketbuf[i + 3072];
        atomicAdd(&cnt[a & 2047], 1);
        atomicAdd(&cnt[c & 2047], 1);
        atomicAdd(&cnt[d & 2047], 1);
        atomicAdd(&cnt[e & 2047], 1);
    }
    for (; i < e1; i += 1024)
        atomicAdd(&cnt[bucketbuf[i] & 2047], 1);
    __syncthreads();
    int base = t * 2;
    int c0 = cnt[base], c1 = cnt[base + 1];
    partials[t] = c0 + c1;
    __syncthreads();
    if (t == 0) {
        int run = 0;
        for (int k = 0; k < 1024; ++k) { int tmp = partials[k]; partials[k] = run; run += tmp; }
    }
    __syncthreads();
    int off = partials[t];
    int cc[2] = {c0, c1};
#pragma unroll
    for (int j = 0; j < 2; ++j) {
        int k = base + j;
        int node = b * 2048 + k;
        if (node < NN) {
            rowStart[node] = e0 + off;
            float di = rsqrtf((float)cc[j] + 1.0f);
            dinv[node] = di;
            p1[node] = x[node] * di;
        }
        off += cc[j];
    }
    if (b == NBUCK - 1 && t == 0) rowStart[NN] = e1;
}

// ---- path A pass 2b: scatter -> per-node CSR, FUSED with layer-1 agg +
//      epilogue. 1024 threads (R15's 512 ran at 21% occupancy, latency-
//      bound); unroll-4 for memory-level parallelism. ----
__global__ __launch_bounds__(1024) void scat2_kernel(const int* __restrict__ bktStart,
                                                     const int* __restrict__ bucketbuf,
                                                     const int* __restrict__ rowStart,
                                                     const float* __restrict__ p1,
                                                     const float* __restrict__ dinv,
                                                     const float* __restrict__ W1,
                                                     const float* __restrict__ b1,
                                                     const float* __restrict__ W2,
                                                     int* __restrict__ edgebuf,
                                                     vhalf4* __restrict__ p2h) {
    __shared__ int   cur[2048];
    __shared__ float acc[2048];
    int b = blockIdx.x, t = threadIdx.x;
    for (int k = t; k < 2048; k += 1024) {
        int node = b * 2048 + k;
        cur[k] = (node < NN) ? rowStart[node] : 0;
        acc[k] = 0.0f;
    }
    __syncthreads();
    int e0 = bktStart[b], e1 = bktStart[b + 1];
    int i = e0 + t;
    for (; i + 3 * 1024 < e1; i += 4 * 1024) {
        int ea = bucketbuf[i];
        int eb = bucketbuf[i + 1024];
        int ec = bucketbuf[i + 2048];
        int ed = bucketbuf[i + 3072];
        int la = ea & 2047, sa = ea >> 11;
        int lb = eb & 2047, sb = eb >> 11;
        int lc = ec & 2047, sc = ec >> 11;
        int ld = ed & 2047, sd = ed >> 11;
        float va = p1[sa];
        float vb = p1[sb];
        float vc = p1[sc];
        float vd = p1[sd];
        int pa = atomicAdd(&cur[la], 1);
        int pb = atomicAdd(&cur[lb], 1);
        int pc = atomicAdd(&cur[lc], 1);
        int pd = atomicAdd(&cur[ld], 1);
        edgebuf[pa] = sa;
        edgebuf[pb] = sb;
        edgebuf[pc] = sc;
        edgebuf[pd] = sd;
        atomicAdd(&acc[la], va);
        atomicAdd(&acc[lb], vb);
        atomicAdd(&acc[lc], vc);
        atomicAdd(&acc[ld], vd);
    }
    for (; i < e1; i += 1024) {
        int e = bucketbuf[i];
        int loc = e & 2047, srcn = e >> 11;
        int pos = atomicAdd(&cur[loc], 1);
        edgebuf[pos] = srcn;
        atomicAdd(&acc[loc], p1[srcn]);
    }
    __syncthreads();
    // fused layer-1 epilogue: h1 = tanh(W1*t + b1); p2h = di * (h1 @ W2)
    for (int k = t; k < 2048; k += 1024) {
        int node = b * 2048 + k;
        if (node < NN) {
            float di = dinv[node];
            float tt = di * (acc[k] + p1[node]);   // norm-agg + self-loop
            float h1[4];
#pragma unroll
            for (int f = 0; f < 4; ++f) h1[f] = tanhf(tt * W1[f] + b1[f]);
            vhalf4 g;
            g.x = (_Float16)(di * (h1[0]*W2[0] + h1[1]*W2[4] + h1[2]*W2[8]  + h1[3]*W2[12]));
            g.y = (_Float16)(di * (h1[0]*W2[1] + h1[1]*W2[5] + h1[2]*W2[9]  + h1[3]*W2[13]));
            g.z = (_Float16)(di * (h1[0]*W2[2] + h1[1]*W2[6] + h1[2]*W2[10] + h1[3]*W2[14]));
            g.w = (_Float16)(di * (h1[0]*W2[3] + h1[1]*W2[7] + h1[2]*W2[11] + h1[3]*W2[15]));
            p2h[node] = g;
        }
    }
}

// ---- path B pass 2 (fallback): within-bin counting sort, as R9 ----
__global__ __launch_bounds__(256) void sortbin_kernel(const int* __restrict__ binStart,
                                                      int* __restrict__ edgebuf,
                                                      const float* __restrict__ x,
                                                      float* __restrict__ dinv,
                                                      float* __restrict__ p1,
                                                      int* __restrict__ rowStart) {
    __shared__ int stage[CAP];
    __shared__ int cnt[256];
    __shared__ int pref[256];
    __shared__ int cur[256];
    int b = blockIdx.x, t = threadIdx.x;
    cnt[t] = 0;
    __syncthreads();
    int e0 = binStart[b], e1 = binStart[b + 1];
    int n = e1 - e0;
    if (n > CAP) n = CAP;
    for (int i = t; i < n; i += 256) {
        int e = edgebuf[e0 + i];
        stage[i] = e;
        atomicAdd(&cnt[e & 255], 1);
    }
    __syncthreads();
    if (t == 0) {
        int run = 0;
        for (int i = 0; i < 256; ++i) { pref[i] = run; run += cnt[i]; }
    }
    __syncthreads();
    cur[t] = pref[t];
    int node = b * 256 + t;
    if (node < NN) {
        rowStart[node] = e0 + pref[t];
        float di = rsqrtf((float)cnt[t] + 1.0f);
        dinv[node] = di;
        p1[node] = x[node] * di;
    }
    if (b == NBIN - 1 && t == 0) rowStart[NN] = binStart[NBIN];
    __syncthreads();
    for (int i = t; i < n; i += 256) {
        int e = stage[i];
        int pos = e0 + atomicAdd(&cur[e & 255], 1);
        edgebuf[pos] = e >> 8;
    }
}

// ---- layer 1 (path B only): per-node register gather of p1 -> p2h ----
__global__ __launch_bounds__(256) void agg1_kernel(const int* __restrict__ rowStart,
                                                   const int* __restrict__ edgebuf,
                                                   const float* __restrict__ p1,
                                                   const float* __restrict__ dinv,
                                                   const float* __restrict__ W1,
                                                   const float* __restrict__ b1,
                                                   const float* __restrict__ W2,
                                                   vhalf4* __restrict__ p2h) {
    int node = blockIdx.x * blockDim.x + threadIdx.x;
    if (node >= NN) return;
    int r0 = rowStart[node], r1 = rowStart[node + 1];
    float s0 = 0.f, s1 = 0.f, s2 = 0.f, s3 = 0.f;
    float s4 = 0.f, s5 = 0.f, s6 = 0.f, s7 = 0.f;
    int k = r0;
    for (; k + 8 <= r1; k += 8) {
        int a = edgebuf[k],     b = edgebuf[k + 1];
        int c = edgebuf[k + 2], d = edgebuf[k + 3];
        int e = edgebuf[k + 4], f = edgebuf[k + 5];
        int g = edgebuf[k + 6], h = edgebuf[k + 7];
        s0 += p1[a]; s1 += p1[b]; s2 += p1[c]; s3 += p1[d];
        s4 += p1[e]; s5 += p1[f]; s6 += p1[g]; s7 += p1[h];
    }
    for (; k < r1; ++k) s0 += p1[edgebuf[k]];
    float acc = ((s0 + s1) + (s2 + s3)) + ((s4 + s5) + (s6 + s7));
    float di = dinv[node];
    float t = di * (acc + p1[node]);
    float h1[4];
#pragma unroll
    for (int f2 = 0; f2 < 4; ++f2) h1[f2] = tanhf(t * W1[f2] + b1[f2]);
    vhalf4 g;
    g.x = (_Float16)(di * (h1[0]*W2[0] + h1[1]*W2[4] + h1[2]*W2[8]  + h1[3]*W2[12]));
    g.y = (_Float16)(di * (h1[0]*W2[1] + h1[1]*W2[5] + h1[2]*W2[9]  + h1[3]*W2[13]));
    g.z = (_Float16)(di * (h1[0]*W2[2] + h1[1]*W2[6] + h1[2]*W2[10] + h1[3]*W2[14]));
    g.w = (_Float16)(di * (h1[0]*W2[3] + h1[1]*W2[7] + h1[2]*W2[11] + h1[3]*W2[15]));
    p2h[node] = g;
}

// ---- layer 2: per-node register gather of p2h (f16x4, 4MB table), ILP-8 ----
__global__ __launch_bounds__(256) void agg2_kernel(const int* __restrict__ rowStart,
                                                   const int* __restrict__ edgebuf,
                                                   const vhalf4* __restrict__ p2h,
                                                   const float* __restrict__ dinv,
                                                   const float* __restrict__ b2,
                                                   const float* __restrict__ W3,
                                                   vhalf2* __restrict__ p3h) {
    int node = blockIdx.x * blockDim.x + threadIdx.x;
    if (node >= NN) return;
    int r0 = rowStart[node], r1 = rowStart[node + 1];
    vfloat4 sA = {0.f, 0.f, 0.f, 0.f};
    vfloat4 sB = {0.f, 0.f, 0.f, 0.f};
    vfloat4 sC = {0.f, 0.f, 0.f, 0.f};
    vfloat4 sD = {0.f, 0.f, 0.f, 0.f};
    int k = r0;
    for (; k + 8 <= r1; k += 8) {
        int a = edgebuf[k],     b = edgebuf[k + 1];
        int c = edgebuf[k + 2], d = edgebuf[k + 3];
        int e = edgebuf[k + 4], f = edgebuf[k + 5];
        int g = edgebuf[k + 6], h = edgebuf[k + 7];
        vhalf4 qa = p2h[a], qb = p2h[b], qc = p2h[c], qd = p2h[d];
        vhalf4 qe = p2h[e], qf = p2h[f], qg = p2h[g], qh = p2h[h];
        sA.x += (float)qa.x + (float)qb.x; sB.x += (float)qc.x + (float)qd.x;
        sA.y += (float)qa.y + (float)qb.y; sB.y += (float)qc.y + (float)qd.y;
        sA.z += (float)qa.z + (float)qb.z; sB.z += (float)qc.z + (float)qd.z;
        sA.w += (float)qa.w + (float)qb.w; sB.w += (float)qc.w + (float)qd.w;
        sC.x += (float)qe.x + (float)qf.x; sD.x += (float)qg.x + (float)qh.x;
        sC.y += (float)qe.y + (float)qf.y; sD.y += (float)qg.y + (float)qh.y;
        sC.z += (float)qe.z + (float)qf.z; sD.z += (float)qg.z + (float)qh.z;
        sC.w += (float)qe.w + (float)qf.w; sD.w += (float)qg.w + (float)qh.w;
    }
    for (; k < r1; ++k) {
        vhalf4 q = p2h[edgebuf[k]];
        sA.x += (float)q.x; sA.y += (float)q.y; sA.z += (float)q.z; sA.w += (float)q.w;
    }
    float di = dinv[node];
    vhalf4 pw = p2h[node];
    float h2[4];
    h2[0] = tanhf(di * (sA.x + sB.x + sC.x + sD.x + (float)pw.x) + b2[0]);
    h2[1] = tanhf(di * (sA.y + sB.y + sC.y + sD.y + (float)pw.y) + b2[1]);
    h2[2] = tanhf(di * (sA.z + sB.z + sC.z + sD.z + (float)pw.z) + b2[2]);
    h2[3] = tanhf(di * (sA.w + sB.w + sC.w + sD.w + (float)pw.w) + b2[3]);
    vhalf2 o;
    o.x = (_Float16)(di * (h2[0]*W3[0] + h2[1]*W3[2] + h2[2]*W3[4] + h2[3]*W3[6]));
    o.y = (_Float16)(di * (h2[0]*W3[1] + h2[1]*W3[3] + h2[2]*W3[5] + h2[3]*W3[7]));
    p3h[node] = o;
}

// ---- layer 3: per-node register gather of p3h (f16x2, 2MB table), ILP-8 ----
__global__ __launch_bounds__(256) void agg3_kernel(const int* __restrict__ rowStart,
                                                   const int* __restrict__ edgebuf,
                                                   const vhalf2* __restrict__ p3h,
                                                   const float* __restrict__ dinv,
                                                   const float* __restrict__ b3,
                                                   const float* __restrict__ Wc,
                                                   const float* __restrict__ bc,
                                                   float* __restrict__ out) {
    int node = blockIdx.x * blockDim.x + threadIdx.x;
    if (node >= NN) return;
    int r0 = rowStart[node], r1 = rowStart[node + 1];
    float ax = 0.f, ay = 0.f, bx = 0.f, by = 0.f;
    float cx = 0.f, cy = 0.f, dx = 0.f, dy = 0.f;
    int k = r0;
    for (; k + 8 <= r1; k += 8) {
        int a = edgebuf[k],     b = edgebuf[k + 1];
        int c = edgebuf[k + 2], d = edgebuf[k + 3];
        int e = edgebuf[k + 4], f = edgebuf[k + 5];
        int g = edgebuf[k + 6], h = edgebuf[k + 7];
        vhalf2 qa = p3h[a], qb = p3h[b], qc = p3h[c], qd = p3h[d];
        vhalf2 qe = p3h[e], qf = p3h[f], qg = p3h[g], qh = p3h[h];
        ax += (float)qa.x + (float)qb.x; bx += (float)qc.x + (float)qd.x;
        ay += (float)qa.y + (float)qb.y; by += (float)qc.y + (float)qd.y;
        cx += (float)qe.x + (float)qf.x; dx += (float)qg.x + (float)qh.x;
        cy += (float)qe.y + (float)qf.y; dy += (float)qg.y + (float)qh.y;
    }
    for (; k < r1; ++k) {
        vhalf2 q = p3h[edgebuf[k]];
        ax += (float)q.x; ay += (float)q.y;
    }
    float di = dinv[node];
    vhalf2 pw = p3h[node];
    float h0 = tanhf(di * (ax + bx + cx + dx + (float)pw.x) + b3[0]);
    float h1 = tanhf(di * (ay + by + cy + dy + (float)pw.y) + b3[1]);
    __builtin_nontemporal_store(h0 * Wc[0] + h1 * Wc[1] + bc[0], out + node);
    vfloat2 hh; hh.x = h0; hh.y = h1;
    __builtin_nontemporal_store(hh, (vfloat2*)(out + NN) + node);
}

// ============================ launch ============================

extern "C" void kernel_launch(void* const* d_in, const int* in_sizes, int n_in,
                              void* d_out, int out_size, void* d_ws, size_t ws_size,
                              hipStream_t stream) {
    const float* x   = (const float*)d_in[0];
    const int*   ei  = (const int*)d_in[1];
    const float* W1  = (const float*)d_in[2];
    const float* b1  = (const float*)d_in[3];
    const float* W2  = (const float*)d_in[4];
    const float* b2  = (const float*)d_in[5];
    const float* W3  = (const float*)d_in[6];
    const float* b3  = (const float*)d_in[7];
    const float* Wc  = (const float*)d_in[8];
    const float* bc  = (const float*)d_in[9];
    float* out = (float*)d_out;
    float* ws  = (float*)d_ws;

    const int* src = ei;
    const int* dst = ei + NE;

    float*  dinv     = ws;
    float*  p1       = ws + (size_t)NN;
    vhalf4* p2h      = (vhalf4*)(ws + 2ull * NN);
    vhalf2* p3h      = (vhalf2*)(ws + 4ull * NN);
    int*    rowStart = (int*)(ws + 5ull * NN);
    int*    tail     = (int*)(ws + 6ull * NN + 1);   // path-specific region

    const int B = 256;
    const int aggGrid = (NN + B - 1) / B;            // 1954

    // path A needs: 6NN+1 + NWGA*NBUCK + NBUCK + (NBUCK+1) + 2*NE units (~141MB)
    const size_t needA = (6ull * NN + 1 + (size_t)NWGA * NBUCK + NBUCK + NBUCK + 1
                          + 2ull * NE) * 4ull;

    if (ws_size >= needA) {
        // ---------- path A: two-level, agg1 fused into scatter ----------
        int* wgHist    = tail;
        int* bktTotal  = wgHist + (size_t)NWGA * NBUCK;
        int* bktStart  = bktTotal + NBUCK;
        int* bucketbuf = bktStart + NBUCK + 1;
        int* edgebuf   = bucketbuf + (size_t)NE;

        hipLaunchKernelGGL(hist_kernel, dim3(NWGA), dim3(B), 0, stream,
                           dst, wgHist, 11, NBUCK, CHUNKA4);
        hipLaunchKernelGGL(scanbins_kernel, dim3(NBUCK), dim3(B), 0, stream,
                           wgHist, bktTotal, NWGA, NBUCK);
        hipLaunchKernelGGL(scantotal_kernel, dim3(1), dim3(512), 0, stream,
                           bktTotal, bktStart, NBUCK);
        hipLaunchKernelGGL(reorder_kernel, dim3(NWGA), dim3(B), 0, stream,
                           src, dst, wgHist, bktStart, bucketbuf, 11, NBUCK, CHUNKA4);
        hipLaunchKernelGGL(count_kernel, dim3(NBUCK), dim3(1024), 0, stream,
                           bktStart, bucketbuf, x, dinv, p1, rowStart);
        hipLaunchKernelGGL(scat2_kernel, dim3(NBUCK), dim3(1024), 0, stream,
                           bktStart, bucketbuf, rowStart, p1, dinv, W1, b1, W2,
                           edgebuf, p2h);
        hipLaunchKernelGGL(agg2_kernel, dim3(aggGrid), dim3(B), 0, stream,
                           rowStart, edgebuf, p2h, dinv, b2, W3, p3h);
        hipLaunchKernelGGL(agg3_kernel, dim3(aggGrid), dim3(B), 0, stream,
                           rowStart, edgebuf, p3h, dinv, b3, Wc, bc, out);
    } else {
        // ---------- path B: fallback (R9 single-level) ----------
        int* wgHist   = tail;
        int* binTotal = wgHist + (size_t)NWGB * NBIN;
        int* binStart = binTotal + NBIN;
        int* edgebuf  = binStart + NBIN + 1;

        hipLaunchKernelGGL(hist_kernel, dim3(NWGB), dim3(B), 0, stream,
                           dst, wgHist, 8, NBIN, CHUNKB4);
        hipLaunchKernelGGL(scanbins_kernel, dim3(NBIN), dim3(B), 0, stream,
                           wgHist, binTotal, NWGB, NBIN);
        hipLaunchKernelGGL(scantotal_kernel, dim3(1), dim3(512), 0, stream,
                           binTotal, binStart, NBIN);
        hipLaunchKernelGGL(reorder_kernel, dim3(NWGB), dim3(B), 0, stream,
                           src, dst, wgHist, binStart, edgebuf, 8, NBIN, CHUNKB4);
        hipLaunchKernelGGL(sortbin_kernel, dim3(NBIN), dim3(B), 0, stream,
                           binStart, edgebuf, x, dinv, p1, rowStart);
        hipLaunchKernelGGL(agg1_kernel, dim3(aggGrid), dim3(B), 0, stream,
                           rowStart, edgebuf, p1, dinv, W1, b1, W2, p2h);
        hipLaunchKernelGGL(agg2_kernel, dim3(aggGrid), dim3(B), 0, stream,
                           rowStart, edgebuf, p2h, dinv, b2, W3, p3h);
        hipLaunchKernelGGL(agg3_kernel, dim3(aggGrid), dim3(B), 0, stream,
                           rowStart, edgebuf, p3h, dinv, b3, Wc, bc, out);
    }
}